// Round 4
// baseline (330.310 us; speedup 1.0000x reference)
//
#include <hip/hip_runtime.h>
#include <math.h>

#define NN 20000
#define NE 640000

typedef __attribute__((ext_vector_type(8))) short short8v;
typedef __attribute__((ext_vector_type(4))) float f32x4;

__device__ inline unsigned short f2bf(float f) {
    unsigned int u = __builtin_bit_cast(unsigned int, f);
    u += 0x7fff + ((u >> 16) & 1);   // RNE
    return (unsigned short)(u >> 16);
}
__device__ inline float bf2f(unsigned short s) {
    unsigned int u = ((unsigned int)s) << 16;
    return __builtin_bit_cast(float, u);
}

__global__ __launch_bounds__(256)
void zero_kernel(unsigned int* __restrict__ p, int n)
{
    int i = blockIdx.x * 256 + threadIdx.x;
    if (i < n) p[i] = 0u;
}

// Wfused[i][m] = sum_p W_ih[i][256+p] * W_dec[p][m]   (768 x 128)
__global__ __launch_bounds__(256)
void wfused_kernel(const float* __restrict__ W_ih, const float* __restrict__ W_dec,
                   float* __restrict__ Wfused)
{
    int idx = blockIdx.x * 256 + threadIdx.x;
    int i = idx >> 7, m = idx & 127;
    const float* wr = W_ih + (size_t)i * 384 + 256;
    float acc = 0.f;
#pragma unroll 4
    for (int p = 0; p < 128; ++p) acc += wr[p] * W_dec[p * 128 + m];
    Wfused[idx] = acc;
}

// Wbig[1024][640] bf16, cols [x(0:256)|h(256:512)|c(512:640)], rows r,z,i_n,h_n
__global__ __launch_bounds__(256)
void pack_kernel(const float* __restrict__ W_ih, const float* __restrict__ W_hh,
                 const float* __restrict__ Wfused, unsigned short* __restrict__ Wbig)
{
    int r = blockIdx.x;            // 1024
    int g = r >> 8, j = r & 255;
    for (int k = threadIdx.x; k < 640; k += 256) {
        float v;
        if (k < 256) {
            v = (g < 3) ? W_ih[(size_t)(g * 256 + j) * 384 + k] : 0.f;
        } else if (k < 512) {
            int sr = (g < 2) ? g * 256 + j : 512 + j;
            v = (g == 2) ? 0.f : W_hh[(size_t)sr * 256 + (k - 256)];
        } else {
            v = (g < 3) ? Wfused[(size_t)(g * 256 + j) * 128 + (k - 512)] : 0.f;
        }
        Wbig[(size_t)r * 640 + k] = f2bf(v);
    }
}

// bias_cat[1024]: r,z: b_ih+b_hh+bdt; i_n: b_ih+bdt; h_n: b_hh
__global__ __launch_bounds__(256)
void bias_kernel(const float* __restrict__ W_ih, const float* __restrict__ b_ih,
                 const float* __restrict__ b_hh, const float* __restrict__ b_dec,
                 float* __restrict__ bias_cat)
{
    int r = blockIdx.x * 256 + threadIdx.x;  // 1024
    int g = r >> 8, j = r & 255;
    float v;
    if (g == 3) {
        v = b_hh[512 + j];
    } else {
        int sr = g * 256 + j;
        float bdt = 0.f;
#pragma unroll 4
        for (int m = 0; m < 128; ++m) bdt += W_ih[(size_t)sr * 384 + 256 + m] * b_dec[m];
        v = b_ih[sr] + bdt + ((g < 2) ? b_hh[sr] : 0.f);
    }
    bias_cat[r] = v;
}

// Ahi/Alo[20000][512] bf16 hi/lo of [x|h]
__global__ __launch_bounds__(256)
void prep_A(const float* __restrict__ x, const float* __restrict__ h,
            unsigned short* __restrict__ Ahi, unsigned short* __restrict__ Alo)
{
    int idx = blockIdx.x * 256 + threadIdx.x;   // 20000*128 quads
    if (idx >= NN * 128) return;
    int row = idx >> 7, col = (idx & 127) * 4;
    const float* src = (col < 256) ? (x + (size_t)row * 256 + col)
                                   : (h + (size_t)row * 256 + (col - 256));
    float4 v = *(const float4*)src;
    ushort4 hi, lo;
    hi.x = f2bf(v.x); lo.x = f2bf(v.x - bf2f(hi.x));
    hi.y = f2bf(v.y); lo.y = f2bf(v.y - bf2f(hi.y));
    hi.z = f2bf(v.z); lo.z = f2bf(v.z - bf2f(hi.z));
    hi.w = f2bf(v.w); lo.w = f2bf(v.w - bf2f(hi.w));
    *(ushort4*)&Ahi[(size_t)row * 512 + col] = hi;
    *(ushort4*)&Alo[(size_t)row * 512 + col] = lo;
}

// Whi/Wlo[128][512] bf16 hi/lo of W_enc
__global__ __launch_bounds__(256)
void prep_W(const float* __restrict__ W_enc,
            unsigned short* __restrict__ Whi, unsigned short* __restrict__ Wlo)
{
    int idx = blockIdx.x * 256 + threadIdx.x;   // 128*128 quads
    int col = (idx & 127) * 4, row = idx >> 7;
    float4 v = *(const float4*)(W_enc + (size_t)row * 512 + col);
    ushort4 hi, lo;
    hi.x = f2bf(v.x); lo.x = f2bf(v.x - bf2f(hi.x));
    hi.y = f2bf(v.y); lo.y = f2bf(v.y - bf2f(hi.y));
    hi.z = f2bf(v.z); lo.z = f2bf(v.z - bf2f(hi.z));
    hi.w = f2bf(v.w); lo.w = f2bf(v.w - bf2f(hi.w));
    *(ushort4*)&Whi[(size_t)row * 512 + col] = hi;
    *(ushort4*)&Wlo[(size_t)row * 512 + col] = lo;
}

// L = [x|h] @ W_enc^T + b_enc via bf16x3 (hi*hi + lo*hi + hi*lo). BM=64,BN=128.
__global__ __launch_bounds__(256)
void enc_gemm(const unsigned short* __restrict__ Ahi, const unsigned short* __restrict__ Alo,
              const unsigned short* __restrict__ Whi, const unsigned short* __restrict__ Wlo,
              const float* __restrict__ b_enc, float* __restrict__ L)
{
    __shared__ __align__(16) short Ah[64][72], Al[64][72];
    __shared__ __align__(16) short Wh[128][72], Wl[128][72];
    const int bm0 = blockIdx.x * 64;
    const int tid = threadIdx.x;
    const int lane = tid & 63;
    const int wave = tid >> 6;
    const int wm = wave >> 1, wn = wave & 1;   // wave: 32 rows x 64 cols
    const int r16 = lane & 15, kg = lane >> 4;

    f32x4 acc[2][4];
#pragma unroll
    for (int i = 0; i < 2; ++i)
#pragma unroll
        for (int j = 0; j < 4; ++j) acc[i][j] = (f32x4){0.f, 0.f, 0.f, 0.f};

    for (int kt = 0; kt < 512; kt += 64) {
#pragma unroll
        for (int it = 0; it < 2; ++it) {
            int seg = tid + it * 256;
            int row = seg >> 3, s = seg & 7;
            int gm = bm0 + row; if (gm >= NN) gm = NN - 1;
            *(short8v*)&Ah[row][s * 8] = *(const short8v*)&Ahi[(size_t)gm * 512 + kt + s * 8];
            *(short8v*)&Al[row][s * 8] = *(const short8v*)&Alo[(size_t)gm * 512 + kt + s * 8];
        }
#pragma unroll
        for (int it = 0; it < 4; ++it) {
            int seg = tid + it * 256;
            int row = seg >> 3, s = seg & 7;
            *(short8v*)&Wh[row][s * 8] = *(const short8v*)&Whi[(size_t)row * 512 + kt + s * 8];
            *(short8v*)&Wl[row][s * 8] = *(const short8v*)&Wlo[(size_t)row * 512 + kt + s * 8];
        }
        __syncthreads();
#pragma unroll
        for (int ks = 0; ks < 2; ++ks) {
            int kc = ks * 32 + kg * 8;
            short8v ah[2], al[2], wh[4], wl[4];
#pragma unroll
            for (int f = 0; f < 2; ++f) {
                ah[f] = *(const short8v*)&Ah[wm * 32 + f * 16 + r16][kc];
                al[f] = *(const short8v*)&Al[wm * 32 + f * 16 + r16][kc];
            }
#pragma unroll
            for (int f = 0; f < 4; ++f) {
                wh[f] = *(const short8v*)&Wh[wn * 64 + f * 16 + r16][kc];
                wl[f] = *(const short8v*)&Wl[wn * 64 + f * 16 + r16][kc];
            }
#pragma unroll
            for (int fi = 0; fi < 2; ++fi)
#pragma unroll
                for (int fj = 0; fj < 4; ++fj) {
                    acc[fi][fj] = __builtin_amdgcn_mfma_f32_16x16x32_bf16(
                        ah[fi], wh[fj], acc[fi][fj], 0, 0, 0);
                    acc[fi][fj] = __builtin_amdgcn_mfma_f32_16x16x32_bf16(
                        al[fi], wh[fj], acc[fi][fj], 0, 0, 0);
                    acc[fi][fj] = __builtin_amdgcn_mfma_f32_16x16x32_bf16(
                        ah[fi], wl[fj], acc[fi][fj], 0, 0, 0);
                }
        }
        __syncthreads();
    }
#pragma unroll
    for (int fi = 0; fi < 2; ++fi) {
        int rg = bm0 + wm * 32 + fi * 16 + kg * 4;
#pragma unroll
        for (int fj = 0; fj < 4; ++fj) {
            int cg = wn * 64 + fj * 16 + r16;
            float bv = b_enc[cg];
#pragma unroll
            for (int i = 0; i < 4; ++i)
                if (rg + i < NN) L[(size_t)(rg + i) * 128 + cg] = acc[fi][fj][i] + bv;
        }
    }
}

// grid-stride; one wave per edge; lane j: argmax pair -> bit; OR-reduce; atomicOr
__global__ __launch_bounds__(256)
void edge_msg_kernel(const float* __restrict__ L, const float* __restrict__ gumbel,
                     const int* __restrict__ src, const int* __restrict__ dst,
                     unsigned int* __restrict__ cbits, int E)
{
    int lane = threadIdx.x & 63;
    int slot = blockIdx.x * 4 + (threadIdx.x >> 6);
    int nslots = gridDim.x * 4;
    for (int e = slot; e < E; e += nslots) {
        int s = src[e];
        float2 g = *(const float2*)&gumbel[(size_t)e * 128 + lane * 2];
        float2 l = *(const float2*)&L[(size_t)s * 128 + lane * 2];
        int choice1 = (l.x + g.x) < (l.y + g.y) ? 1 : 0;
        unsigned int val = 1u << (2 * (lane & 15) + choice1);
        val |= __shfl_xor(val, 1);
        val |= __shfl_xor(val, 2);
        val |= __shfl_xor(val, 4);
        val |= __shfl_xor(val, 8);
        if ((lane & 15) == 0) {
            int d = dst[e];
            atomicOr(&cbits[(size_t)d * 4 + (lane >> 4)], val);
        }
    }
}

// Fused gates GEMM + GRU. Block: 128 rows x 64 hidden cols; wave w: rows [32w,32w+32).
// acc[gate][rowfrag][colfrag]; K = [x(0:256)|h(256:512)|c(512:640)].
__global__ __launch_bounds__(256, 2)
void gates_gru(const unsigned short* __restrict__ Ahi, const unsigned int* __restrict__ cbits,
               const unsigned short* __restrict__ Wbig, const float* __restrict__ bias_cat,
               const float* __restrict__ h, float* __restrict__ out)
{
    __shared__ __align__(16) short As[128][72];
    __shared__ __align__(16) short Ws[256][72];   // 4 gates x 64 rows
    const int bm0 = blockIdx.x * 128;
    const int j0 = blockIdx.y * 64;
    const int tid = threadIdx.x;
    const int lane = tid & 63;
    const int w = tid >> 6;
    const int r16 = lane & 15, kg = lane >> 4;

    f32x4 acc[4][2][4];
#pragma unroll
    for (int g = 0; g < 4; ++g)
#pragma unroll
        for (int i = 0; i < 2; ++i)
#pragma unroll
            for (int j = 0; j < 4; ++j) acc[g][i][j] = (f32x4){0.f, 0.f, 0.f, 0.f};

    for (int kt = 0; kt < 10; ++kt) {
        const int kc0 = kt * 64;
#pragma unroll
        for (int it = 0; it < 4; ++it) {          // As: 128 rows x 8 segs
            int seg = tid + it * 256;
            int row = seg >> 3, s = seg & 7;
            int gm = bm0 + row; if (gm >= NN) gm = NN - 1;
            int kc = kc0 + s * 8;
            short8v sv;
            if (kc < 512) {
                sv = *(const short8v*)&Ahi[(size_t)gm * 512 + kc];
            } else {
                int mb = kc - 512;
                unsigned int word = cbits[gm * 4 + (mb >> 5)];
                unsigned int byte = (word >> (mb & 31)) & 0xffu;
#pragma unroll
                for (int t = 0; t < 8; ++t)
                    sv[t] = ((byte >> t) & 1u) ? (short)0x3F80 : (short)0;
            }
            *(short8v*)&As[row][s * 8] = sv;
        }
#pragma unroll
        for (int it = 0; it < 8; ++it) {          // Ws: 256 rows x 8 segs
            int seg = tid + it * 256;
            int row = seg >> 3, s = seg & 7;
            int g = row >> 6, jj = row & 63;
            *(short8v*)&Ws[row][s * 8] =
                *(const short8v*)&Wbig[(size_t)(g * 256 + j0 + jj) * 640 + kc0 + s * 8];
        }
        __syncthreads();
        const int active = (kt < 4 || kt >= 8) ? 0x7 : 0xB;  // r,z,i | r,z,hn
#pragma unroll
        for (int ks = 0; ks < 2; ++ks) {
            int kc = ks * 32 + kg * 8;
            short8v a[2];
            a[0] = *(const short8v*)&As[w * 32 + r16][kc];
            a[1] = *(const short8v*)&As[w * 32 + 16 + r16][kc];
#pragma unroll
            for (int g = 0; g < 4; ++g) {
                if (!((active >> g) & 1)) continue;
                short8v b[4];
#pragma unroll
                for (int f = 0; f < 4; ++f)
                    b[f] = *(const short8v*)&Ws[g * 64 + f * 16 + r16][kc];
#pragma unroll
                for (int fi = 0; fi < 2; ++fi)
#pragma unroll
                    for (int fj = 0; fj < 4; ++fj)
                        acc[g][fi][fj] = __builtin_amdgcn_mfma_f32_16x16x32_bf16(
                            a[fi], b[fj], acc[g][fi][fj], 0, 0, 0);
            }
        }
        __syncthreads();
    }
    // GRU epilogue
#pragma unroll
    for (int fi = 0; fi < 2; ++fi) {
        int rg = bm0 + w * 32 + fi * 16 + kg * 4;
#pragma unroll
        for (int fj = 0; fj < 4; ++fj) {
            int cg = j0 + fj * 16 + r16;
            float br = bias_cat[cg],      bz = bias_cat[256 + cg];
            float bi = bias_cat[512 + cg], bh = bias_cat[768 + cg];
#pragma unroll
            for (int i = 0; i < 4; ++i) {
                int m = rg + i;
                if (m >= NN) continue;
                float rp = acc[0][fi][fj][i] + br;
                float zp = acc[1][fi][fj][i] + bz;
                float ip = acc[2][fi][fj][i] + bi;
                float hp = acc[3][fi][fj][i] + bh;
                float hv = h[(size_t)m * 256 + cg];
                float r = 1.f / (1.f + __expf(-rp));
                float z = 1.f / (1.f + __expf(-zp));
                float nn2 = tanhf(ip + r * hp);
                out[(size_t)m * 256 + cg] = (1.f - z) * nn2 + z * hv;
            }
        }
    }
}

extern "C" void kernel_launch(void* const* d_in, const int* in_sizes, int n_in,
                              void* d_out, int out_size, void* d_ws, size_t ws_size,
                              hipStream_t stream)
{
    const float* x     = (const float*)d_in[0];
    const float* h     = (const float*)d_in[1];
    const float* W_enc = (const float*)d_in[2];
    const float* b_enc = (const float*)d_in[3];
    const float* W_dec = (const float*)d_in[4];
    const float* b_dec = (const float*)d_in[5];
    const float* W_ih  = (const float*)d_in[6];
    const float* b_ih  = (const float*)d_in[7];
    const float* W_hh  = (const float*)d_in[8];
    const float* b_hh  = (const float*)d_in[9];
    const float* gumbel = (const float*)d_in[10];
    const int*   src   = (const int*)d_in[11];
    const int*   dst   = (const int*)d_in[12];
    float* out = (float*)d_out;

    char* ws = (char*)d_ws;
    float*          L        = (float*)(ws);                       // 10,240,000
    unsigned int*   cbits    = (unsigned int*)(ws + 10240000);     //    320,000
    float*          Wfused   = (float*)(ws + 10560000);            //    393,216
    unsigned short* Wbig     = (unsigned short*)(ws + 10953216);   //  1,310,720
    float*          bias_cat = (float*)(ws + 12263936);            //      4,096
    unsigned short* Ahi      = (unsigned short*)(ws + 12268032);   // 20,480,000
    unsigned short* Alo      = (unsigned short*)(ws + 32748032);   // 20,480,000
    unsigned short* Whi      = (unsigned short*)(ws + 53228032);   //    131,072
    unsigned short* Wlo      = (unsigned short*)(ws + 53359104);   //    131,072

    zero_kernel<<<313, 256, 0, stream>>>(cbits, NN * 4);
    wfused_kernel<<<384, 256, 0, stream>>>(W_ih, W_dec, Wfused);
    pack_kernel<<<1024, 256, 0, stream>>>(W_ih, W_hh, Wfused, Wbig);
    bias_kernel<<<4, 256, 0, stream>>>(W_ih, b_ih, b_hh, b_dec, bias_cat);
    prep_A<<<10000, 256, 0, stream>>>(x, h, Ahi, Alo);
    prep_W<<<64, 256, 0, stream>>>(W_enc, Whi, Wlo);

    enc_gemm<<<313, 256, 0, stream>>>(Ahi, Alo, Whi, Wlo, b_enc, L);

    edge_msg_kernel<<<2048, 256, 0, stream>>>(L, gumbel, src, dst, cbits, NE);

    gates_gru<<<dim3(157, 4), 256, 0, stream>>>(Ahi, cbits, Wbig, bias_cat, h, out);
}

// Round 5
// 240.559 us; speedup vs baseline: 1.3731x; 1.3731x over previous
//
#include <hip/hip_runtime.h>
#include <math.h>

#define NN 20000
#define NE 640000

typedef __attribute__((ext_vector_type(8))) short short8v;
typedef __attribute__((ext_vector_type(4))) float f32x4;

__device__ inline unsigned short f2bf(float f) {
    unsigned int u = __builtin_bit_cast(unsigned int, f);
    u += 0x7fff + ((u >> 16) & 1);   // RNE
    return (unsigned short)(u >> 16);
}
__device__ inline float bf2f(unsigned short s) {
    unsigned int u = ((unsigned int)s) << 16;
    return __builtin_bit_cast(float, u);
}
// async global->LDS, 16B per lane; dest = uniform base + lane*16
__device__ inline void gload16(const unsigned short* g, short* l) {
    __builtin_amdgcn_global_load_lds(
        (const __attribute__((address_space(1))) unsigned int*)g,
        (__attribute__((address_space(3))) unsigned int*)l, 16, 0, 0);
}

// ---- prep: Wbig pack (+ fused W_dec folding), bias_cat, cbits zero ----
// Wbig[1024][640] bf16, cols [x(0:256)|h(256:512)|c(512:640)], row groups r,z,i_n,h_n
__global__ __launch_bounds__(256)
void prep_kernel(const float* __restrict__ W_ih, const float* __restrict__ W_hh,
                 const float* __restrict__ W_dec, const float* __restrict__ b_ih,
                 const float* __restrict__ b_hh, const float* __restrict__ b_dec,
                 unsigned short* __restrict__ Wbig, float* __restrict__ bias_cat,
                 unsigned int* __restrict__ cbits)
{
    int r = blockIdx.x;              // 1024
    int tid = threadIdx.x;
    int zi = r * 256 + tid;
    if (zi < NN * 4) cbits[zi] = 0u;
    int g = r >> 8, j = r & 255;
    for (int k = tid; k < 512; k += 256) {
        float v;
        if (k < 256) {
            v = (g < 3) ? W_ih[(size_t)(g * 256 + j) * 384 + k] : 0.f;
        } else {
            int sr = (g < 2) ? g * 256 + j : 512 + j;
            v = (g == 2) ? 0.f : W_hh[(size_t)sr * 256 + (k - 256)];
        }
        Wbig[(size_t)r * 640 + k] = f2bf(v);
    }
    if (tid < 128) {                 // c-cols: (W_ih[:,256:] @ W_dec)[r][tid]
        float acc = 0.f;
        if (g < 3) {
            const float* wr = W_ih + (size_t)(g * 256 + j) * 384 + 256;
#pragma unroll 4
            for (int p = 0; p < 128; ++p) acc += wr[p] * W_dec[p * 128 + tid];
        }
        Wbig[(size_t)r * 640 + 512 + tid] = f2bf(acc);
    } else if (tid == 128) {
        float v;
        if (g == 3) {
            v = b_hh[512 + j];
        } else {
            int sr = g * 256 + j;
            float bdt = 0.f;
            for (int m = 0; m < 128; ++m) bdt += W_ih[(size_t)sr * 384 + 256 + m] * b_dec[m];
            v = b_ih[sr] + bdt + ((g < 2) ? b_hh[sr] : 0.f);
        }
        bias_cat[r] = v;
    }
}

// ---- enc: L = [x|h] @ W_enc^T + b_enc, bf16x3; side-writes Abig[:,0:512] hi ----
__global__ __launch_bounds__(256)
void enc_gemm(const float* __restrict__ x, const float* __restrict__ h,
              const float* __restrict__ W_enc, const float* __restrict__ b_enc,
              float* __restrict__ L, unsigned short* __restrict__ Abig)
{
    __shared__ __align__(16) short Ah[64][72], Al[64][72];
    __shared__ __align__(16) short Wh[128][72], Wl[128][72];
    const int bm0 = blockIdx.x * 64;
    const int tid = threadIdx.x;
    const int lane = tid & 63;
    const int wave = tid >> 6;
    const int wm = wave >> 1, wn = wave & 1;   // wave: 32 rows x 64 cols
    const int r16 = lane & 15, kg = lane >> 4;

    f32x4 acc[2][4];
#pragma unroll
    for (int i = 0; i < 2; ++i)
#pragma unroll
        for (int j = 0; j < 4; ++j) acc[i][j] = (f32x4){0.f, 0.f, 0.f, 0.f};

    for (int kt = 0; kt < 512; kt += 64) {
#pragma unroll
        for (int it = 0; it < 2; ++it) {        // A: 64 rows x 8 segs
            int seg = tid + it * 256;
            int row = seg >> 3, s = seg & 7;
            int kc = kt + s * 8;
            int gm = bm0 + row; if (gm >= NN) gm = NN - 1;
            const float* p = (kc < 256) ? (x + (size_t)gm * 256 + kc)
                                        : (h + (size_t)gm * 256 + (kc - 256));
            float4 v0 = *(const float4*)p;
            float4 v1 = *(const float4*)(p + 4);
            float vv[8] = {v0.x, v0.y, v0.z, v0.w, v1.x, v1.y, v1.z, v1.w};
            short8v hi, lo;
#pragma unroll
            for (int t = 0; t < 8; ++t) {
                unsigned short hb = f2bf(vv[t]);
                hi[t] = (short)hb;
                lo[t] = (short)f2bf(vv[t] - bf2f(hb));
            }
            *(short8v*)&Ah[row][s * 8] = hi;
            *(short8v*)&Al[row][s * 8] = lo;
            *(short8v*)&Abig[(size_t)gm * 640 + kc] = hi;
        }
#pragma unroll
        for (int it = 0; it < 4; ++it) {        // W: 128 rows x 8 segs
            int seg = tid + it * 256;
            int row = seg >> 3, s = seg & 7;
            const float* q = W_enc + (size_t)row * 512 + kt + s * 8;
            float4 v0 = *(const float4*)q;
            float4 v1 = *(const float4*)(q + 4);
            float vv[8] = {v0.x, v0.y, v0.z, v0.w, v1.x, v1.y, v1.z, v1.w};
            short8v hi, lo;
#pragma unroll
            for (int t = 0; t < 8; ++t) {
                unsigned short hb = f2bf(vv[t]);
                hi[t] = (short)hb;
                lo[t] = (short)f2bf(vv[t] - bf2f(hb));
            }
            *(short8v*)&Wh[row][s * 8] = hi;
            *(short8v*)&Wl[row][s * 8] = lo;
        }
        __syncthreads();
#pragma unroll
        for (int ks = 0; ks < 2; ++ks) {
            int kc = ks * 32 + kg * 8;
            short8v ah[2], al[2], wh[4], wl[4];
#pragma unroll
            for (int f = 0; f < 2; ++f) {
                ah[f] = *(const short8v*)&Ah[wm * 32 + f * 16 + r16][kc];
                al[f] = *(const short8v*)&Al[wm * 32 + f * 16 + r16][kc];
            }
#pragma unroll
            for (int f = 0; f < 4; ++f) {
                wh[f] = *(const short8v*)&Wh[wn * 64 + f * 16 + r16][kc];
                wl[f] = *(const short8v*)&Wl[wn * 64 + f * 16 + r16][kc];
            }
#pragma unroll
            for (int fi = 0; fi < 2; ++fi)
#pragma unroll
                for (int fj = 0; fj < 4; ++fj) {
                    acc[fi][fj] = __builtin_amdgcn_mfma_f32_16x16x32_bf16(
                        ah[fi], wh[fj], acc[fi][fj], 0, 0, 0);
                    acc[fi][fj] = __builtin_amdgcn_mfma_f32_16x16x32_bf16(
                        al[fi], wh[fj], acc[fi][fj], 0, 0, 0);
                    acc[fi][fj] = __builtin_amdgcn_mfma_f32_16x16x32_bf16(
                        ah[fi], wl[fj], acc[fi][fj], 0, 0, 0);
                }
        }
        __syncthreads();
    }
#pragma unroll
    for (int fi = 0; fi < 2; ++fi) {
        int rg = bm0 + wm * 32 + fi * 16 + kg * 4;
#pragma unroll
        for (int fj = 0; fj < 4; ++fj) {
            int cg = wn * 64 + fj * 16 + r16;
            float bv = b_enc[cg];
#pragma unroll
            for (int i = 0; i < 4; ++i)
                if (rg + i < NN) L[(size_t)(rg + i) * 128 + cg] = acc[fi][fj][i] + bv;
        }
    }
}

// ---- edge: per-edge gumbel argmax -> OR into cbits ----
__global__ __launch_bounds__(256)
void edge_msg_kernel(const float* __restrict__ L, const float* __restrict__ gumbel,
                     const int* __restrict__ src, const int* __restrict__ dst,
                     unsigned int* __restrict__ cbits, int E)
{
    int lane = threadIdx.x & 63;
    int slot = blockIdx.x * 4 + (threadIdx.x >> 6);
    int nslots = gridDim.x * 4;
    for (int e = slot; e < E; e += nslots) {
        int s = src[e];
        float2 g = *(const float2*)&gumbel[(size_t)e * 128 + lane * 2];
        float2 l = *(const float2*)&L[(size_t)s * 128 + lane * 2];
        int choice1 = (l.x + g.x) < (l.y + g.y) ? 1 : 0;
        unsigned int val = 1u << (2 * (lane & 15) + choice1);
        val |= __shfl_xor(val, 1);
        val |= __shfl_xor(val, 2);
        val |= __shfl_xor(val, 4);
        val |= __shfl_xor(val, 8);
        if ((lane & 15) == 0) {
            int d = dst[e];
            atomicOr(&cbits[(size_t)d * 4 + (lane >> 4)], val);
        }
    }
}

// ---- expand cbits -> Abig[:,512:640] bf16 0/1 ----
__global__ __launch_bounds__(256)
void expand_c(const unsigned int* __restrict__ cbits, unsigned short* __restrict__ Abig)
{
    int idx = blockIdx.x * 256 + threadIdx.x;   // NN*4
    if (idx >= NN * 4) return;
    int n = idx >> 2, w = idx & 3;
    unsigned int bits = cbits[idx];
    unsigned short* p = Abig + (size_t)n * 640 + 512 + w * 32;
#pragma unroll
    for (int t = 0; t < 32; t += 8) {
        short8v v;
#pragma unroll
        for (int u = 0; u < 8; ++u)
            v[u] = ((bits >> (t + u)) & 1u) ? (short)0x3F80 : (short)0;
        *(short8v*)&p[t] = v;
    }
}

// ---- fused gates GEMM + GRU ----
// Block: 64 rows x 64 hidden cols, all 4 gates. Wave w: cols [16w,16w+16).
// K layout [x(0:256)|h(256:512)|c(512:640)]; per-kt active-gate mask.
// LDS linear + XOR-swizzle (both sides), staged via global_load_lds.
__global__ __launch_bounds__(256)
void gates_gru(const unsigned short* __restrict__ Abig,
               const unsigned short* __restrict__ Wbig,
               const float* __restrict__ bias_cat,
               const float* __restrict__ h, float* __restrict__ out)
{
    __shared__ __align__(16) short As[64 * 64];     // 8 KB
    __shared__ __align__(16) short Ws[256 * 64];    // 32 KB
    const int bm0 = blockIdx.x * 64;
    const int j0  = blockIdx.y * 64;
    const int tid = threadIdx.x;
    const int lane = tid & 63;
    const int w = tid >> 6;
    const int r16 = lane & 15, kg = lane >> 4;
    const int sw = r16 & 7;

    f32x4 acc[4][4];
#pragma unroll
    for (int g = 0; g < 4; ++g)
#pragma unroll
        for (int i = 0; i < 4; ++i) acc[g][i] = (f32x4){0.f, 0.f, 0.f, 0.f};

    for (int kt = 0; kt < 10; ++kt) {
        const int kc0 = kt * 64;
        // As: 8 chunks of 64x16B; chunk = w*2+it (uniform per wave)
#pragma unroll
        for (int it = 0; it < 2; ++it) {
            int chunk = w * 2 + it;
            int slot = chunk * 64 + lane;
            int row = slot >> 3, gch = slot & 7;
            int gm = bm0 + row; if (gm >= NN) gm = NN - 1;
            gload16(Abig + (size_t)gm * 640 + kc0 + ((gch ^ (row & 7)) << 3),
                    As + chunk * 512);
        }
        // Ws: 32 chunks; Wbig row = gate*256 + j0 + (row&63)
#pragma unroll
        for (int it = 0; it < 8; ++it) {
            int chunk = w * 8 + it;
            int slot = chunk * 64 + lane;
            int row = slot >> 3, gch = slot & 7;
            int wr = ((row >> 6) << 8) + j0 + (row & 63);
            gload16(Wbig + (size_t)wr * 640 + kc0 + ((gch ^ (row & 7)) << 3),
                    Ws + chunk * 512);
        }
        asm volatile("s_waitcnt vmcnt(0)" ::: "memory");
        __syncthreads();
        const int active = (kt >= 4 && kt < 8) ? 0xB : 0x7;  // r,z,hn | r,z,in
#pragma unroll
        for (int ks = 0; ks < 2; ++ks) {
            int gsel = (ks * 4 + kg) ^ sw;
            short8v a[4], b[4];
#pragma unroll
            for (int fi = 0; fi < 4; ++fi)
                a[fi] = *(const short8v*)&As[(fi * 16 + r16) * 64 + gsel * 8];
#pragma unroll
            for (int g = 0; g < 4; ++g)
                if ((active >> g) & 1)
                    b[g] = *(const short8v*)&Ws[(g * 64 + w * 16 + r16) * 64 + gsel * 8];
#pragma unroll
            for (int g = 0; g < 4; ++g) {
                if (!((active >> g) & 1)) continue;
#pragma unroll
                for (int fi = 0; fi < 4; ++fi)
                    acc[g][fi] = __builtin_amdgcn_mfma_f32_16x16x32_bf16(
                        a[fi], b[g], acc[g][fi], 0, 0, 0);
            }
        }
        __syncthreads();
    }
    // GRU epilogue: row = bm0 + fi*16 + kg*4 + i, col = j0 + w*16 + r16
    const int cg = j0 + w * 16 + r16;
    const float br = bias_cat[cg],       bz = bias_cat[256 + cg];
    const float bi = bias_cat[512 + cg], bh = bias_cat[768 + cg];
#pragma unroll
    for (int fi = 0; fi < 4; ++fi) {
        int rg = bm0 + fi * 16 + kg * 4;
#pragma unroll
        for (int i = 0; i < 4; ++i) {
            int m = rg + i;
            if (m >= NN) continue;
            float rp = acc[0][fi][i] + br;
            float zp = acc[1][fi][i] + bz;
            float ip = acc[2][fi][i] + bi;
            float hp = acc[3][fi][i] + bh;
            float hv = h[(size_t)m * 256 + cg];
            float r = 1.f / (1.f + __expf(-rp));
            float z = 1.f / (1.f + __expf(-zp));
            float nn2 = tanhf(ip + r * hp);
            out[(size_t)m * 256 + cg] = (1.f - z) * nn2 + z * hv;
        }
    }
}

extern "C" void kernel_launch(void* const* d_in, const int* in_sizes, int n_in,
                              void* d_out, int out_size, void* d_ws, size_t ws_size,
                              hipStream_t stream)
{
    const float* x     = (const float*)d_in[0];
    const float* h     = (const float*)d_in[1];
    const float* W_enc = (const float*)d_in[2];
    const float* b_enc = (const float*)d_in[3];
    const float* W_dec = (const float*)d_in[4];
    const float* b_dec = (const float*)d_in[5];
    const float* W_ih  = (const float*)d_in[6];
    const float* b_ih  = (const float*)d_in[7];
    const float* W_hh  = (const float*)d_in[8];
    const float* b_hh  = (const float*)d_in[9];
    const float* gumbel = (const float*)d_in[10];
    const int*   src   = (const int*)d_in[11];
    const int*   dst   = (const int*)d_in[12];
    float* out = (float*)d_out;

    char* ws = (char*)d_ws;
    float*          L        = (float*)(ws);                       // 10,240,000
    unsigned int*   cbits    = (unsigned int*)(ws + 10240000);     //    320,000
    unsigned short* Wbig     = (unsigned short*)(ws + 10560000);   //  1,310,720
    float*          bias_cat = (float*)(ws + 11870720);            //      4,096
    unsigned short* Abig     = (unsigned short*)(ws + 11874816);   // 25,600,000

    prep_kernel<<<1024, 256, 0, stream>>>(W_ih, W_hh, W_dec, b_ih, b_hh, b_dec,
                                          Wbig, bias_cat, cbits);
    enc_gemm<<<313, 256, 0, stream>>>(x, h, W_enc, b_enc, L, Abig);
    edge_msg_kernel<<<2048, 256, 0, stream>>>(L, gumbel, src, dst, cbits, NE);
    expand_c<<<(NN * 4 + 255) / 256, 256, 0, stream>>>(cbits, Abig);
    gates_gru<<<dim3(313, 4), 256, 0, stream>>>(Abig, Wbig, bias_cat, h, out);
}